// Round 3
// baseline (388.542 us; speedup 1.0000x reference)
//
#include <hip/hip_runtime.h>
#include <hip/hip_bf16.h>
#include <math.h>

#define C_DIM 2048
#define E_DIM 64
#define TB    32        // tokens per block (k_router)
#define KC    256       // k per LDS tile

typedef __attribute__((ext_vector_type(8))) short bf16x8;
typedef __attribute__((ext_vector_type(4))) float f32x4;

union cvt8 { bf16x8 v; __hip_bfloat162 h[4]; };

__device__ __forceinline__ bf16x8 pack8(float4 a, float4 b) {
    cvt8 u;
    u.h[0] = __float22bfloat162_rn(make_float2(a.x, a.y));
    u.h[1] = __float22bfloat162_rn(make_float2(a.z, a.w));
    u.h[2] = __float22bfloat162_rn(make_float2(b.x, b.y));
    u.h[3] = __float22bfloat162_rn(make_float2(b.z, b.w));
    return u.v;
}

// ---------------- K1: bf16-MFMA noisy logits -> top-4 candidates -> exact
// fp64 refine of candidates -> top-2 + softmax. One kernel, one x pass. ------
__launch_bounds__(256)
__global__ void k_router(const float* __restrict__ x, const float* __restrict__ w,
                         int* __restrict__ idx0, int* __restrict__ idx1,
                         float* __restrict__ probs, int N)
{
    __shared__ __align__(16) char smem[49152];
    short* xs = (short*)smem;                   // [TB][KC] bf16, swizzled granules
    short* ws = (short*)(smem + TB * KC * 2);   // [E_DIM][KC]

    const int tid  = threadIdx.x;
    const int lane = tid & 63;
    const int wid  = tid >> 6;
    const int quad = lane >> 4;
    const int l15  = lane & 15;
    const int t0   = blockIdx.x * TB;
    const int tq   = (wid & 1) * 16;     // wave's token base (m-tile)
    const int e0   = (wid >> 1) * 32;    // wave's expert base (two n-tiles)

    f32x4 acc0 = {0.f, 0.f, 0.f, 0.f};
    f32x4 acc1 = {0.f, 0.f, 0.f, 0.f};

    for (int kb = 0; kb < C_DIM; kb += KC) {
        __syncthreads();
        // stage x tile: 32 rows x 32 granules (granule = 8 bf16 = 16B)
#pragma unroll
        for (int i = 0; i < 4; ++i) {
            int id = tid + 256 * i;
            int r = id >> 5, g = id & 31;
            const float* src = x + (size_t)(t0 + r) * C_DIM + kb + g * 8;
            float4 a = *(const float4*)src;
            float4 b = *(const float4*)(src + 4);
            *(bf16x8*)&xs[r * KC + ((g ^ (r & 7)) * 8)] = pack8(a, b);
        }
        // stage w tile: 64 rows x 32 granules
#pragma unroll
        for (int i = 0; i < 8; ++i) {
            int id = tid + 256 * i;
            int r = id >> 5, g = id & 31;
            const float* src = w + (size_t)r * C_DIM + kb + g * 8;
            float4 a = *(const float4*)src;
            float4 b = *(const float4*)(src + 4);
            *(bf16x8*)&ws[r * KC + ((g ^ (r & 7)) * 8)] = pack8(a, b);
        }
        __syncthreads();

        const int ar  = tq + l15;        // A row (token within tile)
        const int br0 = e0 + l15;        // B rows (expert = n within tile)
        const int br1 = e0 + 16 + l15;
#pragma unroll
        for (int s = 0; s < KC / 32; ++s) {
            int g = s * 4 + quad;        // lane's k-granule for this K=32 step
            bf16x8 af  = *(const bf16x8*)&xs[ar  * KC + ((g ^ (ar  & 7)) * 8)];
            bf16x8 bf0 = *(const bf16x8*)&ws[br0 * KC + ((g ^ (br0 & 7)) * 8)];
            bf16x8 bf1 = *(const bf16x8*)&ws[br1 * KC + ((g ^ (br1 & 7)) * 8)];
            acc0 = __builtin_amdgcn_mfma_f32_16x16x32_bf16(af, bf0, acc0, 0, 0, 0);
            acc1 = __builtin_amdgcn_mfma_f32_16x16x32_bf16(af, bf1, acc1, 0, 0, 0);
        }
    }

    // ---- noisy logits -> LDS (reuse tile memory) ----
    __syncthreads();
    float*  L    = (float*)smem;                                   // [TB][65]
    int*    cand = (int*)(smem + TB * (E_DIM + 1) * 4);            // [TB][4]
    double* dsum = (double*)(smem + TB * (E_DIM + 1) * 4 + TB * 16); // [TB*4][2]

#pragma unroll
    for (int reg = 0; reg < 4; ++reg) {
        int t = tq + quad * 4 + reg;     // C/D: row = quad*4+reg, col = lane&15
        L[t * (E_DIM + 1) + e0 + l15]      = acc0[reg];
        L[t * (E_DIM + 1) + e0 + 16 + l15] = acc1[reg];
    }
    __syncthreads();

    // ---- top-4 candidates per token (noisy, superset of true top-2) ----
    for (int ti = 0; ti < 8; ++ti) {
        int t = wid * 8 + ti;
        float cur = L[t * (E_DIM + 1) + lane];
#pragma unroll
        for (int r = 0; r < 4; ++r) {
            float a = cur; int ix = lane;
#pragma unroll
            for (int off = 32; off > 0; off >>= 1) {
                float oa = __shfl_down(a, off, 64);
                int   oi = __shfl_down(ix, off, 64);
                if (oa > a || (oa == a && oi < ix)) { a = oa; ix = oi; }
            }
            int win = __shfl(ix, 0, 64);
            if (lane == 0) cand[t * 4 + r] = win;
            if (lane == win) cur = -3.0e38f;
        }
    }
    __syncthreads();

    // ---- exact refine: fp32 16-chain + fp64 accumulate (absmax-0 numerics) ----
    {
        int p = tid >> 1;        // (token, cand) pair 0..127
        int h = tid & 1;         // k-half
        int t = p >> 2;
        int c = cand[t * 4 + (p & 3)];
        const float* xr = x + (size_t)(t0 + t) * C_DIM + h * (C_DIM / 2);
        const float* wr = w + (size_t)c * C_DIM + h * (C_DIM / 2);
        double d = 0.0;
        for (int k = 0; k < C_DIM / 2; k += 16) {
            float4 x0 = *(const float4*)(xr + k);
            float4 x1 = *(const float4*)(xr + k + 4);
            float4 x2 = *(const float4*)(xr + k + 8);
            float4 x3 = *(const float4*)(xr + k + 12);
            float4 w0 = *(const float4*)(wr + k);
            float4 w1 = *(const float4*)(wr + k + 4);
            float4 w2 = *(const float4*)(wr + k + 8);
            float4 w3 = *(const float4*)(wr + k + 12);
            float f;
            f = x0.x * w0.x;
            f = fmaf(x0.y, w0.y, f); f = fmaf(x0.z, w0.z, f); f = fmaf(x0.w, w0.w, f);
            f = fmaf(x1.x, w1.x, f); f = fmaf(x1.y, w1.y, f); f = fmaf(x1.z, w1.z, f);
            f = fmaf(x1.w, w1.w, f);
            f = fmaf(x2.x, w2.x, f); f = fmaf(x2.y, w2.y, f); f = fmaf(x2.z, w2.z, f);
            f = fmaf(x2.w, w2.w, f);
            f = fmaf(x3.x, w3.x, f); f = fmaf(x3.y, w3.y, f); f = fmaf(x3.z, w3.z, f);
            f = fmaf(x3.w, w3.w, f);
            d += (double)f;
        }
        dsum[p * 2 + h] = d;
    }
    __syncthreads();

    // ---- exact top-2 among candidates (ties: lower expert index) ----
    if (tid < TB) {
        int t = tid;
        double v[4]; int e[4];
#pragma unroll
        for (int c = 0; c < 4; ++c) {
            v[c] = dsum[(t * 4 + c) * 2] + dsum[(t * 4 + c) * 2 + 1];
            e[c] = cand[t * 4 + c];
        }
        int b0 = 0;
#pragma unroll
        for (int c = 1; c < 4; ++c)
            if (v[c] > v[b0] || (v[c] == v[b0] && e[c] < e[b0])) b0 = c;
        int b1 = (b0 == 0) ? 1 : 0;
#pragma unroll
        for (int c = 0; c < 4; ++c) {
            if (c == b0 || c == b1) continue;
            if (v[c] > v[b1] || (v[c] == v[b1] && e[c] < e[b1])) b1 = c;
        }
        int n = t0 + t;
        float p0 = 1.0f / (1.0f + expf((float)(v[b1] - v[b0])));
        idx0[n] = e[b0];
        idx1[n] = e[b1];
        probs[2 * n]     = p0;
        probs[2 * n + 1] = 1.0f - p0;
    }
}

// ---------------- K2: rank scan, 128 independent waves (expert x k-pass) ----
__launch_bounds__(64)
__global__ void k_scan(const int* __restrict__ idx0, const int* __restrict__ idx1,
                       int* __restrict__ r0, int* __restrict__ r1, int N)
{
    const int e    = blockIdx.x >> 1;
    const int pass = blockIdx.x & 1;
    const int lane = threadIdx.x;
    const unsigned long long lt = (1ull << lane) - 1ull;
    int running = 0;

    if (pass == 1) {
        // k=1 ranks start at expert e's total k=0 count
        for (int base = 0; base < N; base += 512) {
            int v[8];
#pragma unroll
            for (int j = 0; j < 8; ++j) v[j] = idx0[base + j * 64 + lane];
#pragma unroll
            for (int j = 0; j < 8; ++j) running += __popcll(__ballot(v[j] == e));
        }
    }
    const int* idx = pass ? idx1 : idx0;
    int*       r   = pass ? r1   : r0;
    for (int base = 0; base < N; base += 512) {
        int v[8];
#pragma unroll
        for (int j = 0; j < 8; ++j) v[j] = idx[base + j * 64 + lane];
#pragma unroll
        for (int j = 0; j < 8; ++j) {
            bool p = (v[j] == e);
            unsigned long long b = __ballot(p);
            if (p) r[base + j * 64 + lane] = running + __popcll(b & lt);
            running += __popcll(b);
        }
    }
}

// ---------------- K3: one-hot capacity mask + tail outputs (fused) ----------
__launch_bounds__(256)
__global__ void k_mask_tail(const int* __restrict__ idx0, const int* __restrict__ idx1,
                            const int* __restrict__ r0, const int* __restrict__ r1,
                            const float* __restrict__ probs,
                            float* __restrict__ out, int N, int cap)
{
    int f = blockIdx.x * 256 + threadIdx.x;   // float4 index, total N*32
    int n   = f >> 5;
    int rem = (f & 31) * 4;       // 0..124 within the token's 128 floats
    int k   = rem >> 6;           // 0 or 1
    int e0  = rem & 63;
    int ix = k ? idx1[n] : idx0[n];
    int rr = k ? r1[n]   : r0[n];
    float val = (rr < cap) ? 1.0f : 0.0f;
    float4 o = make_float4(0.f, 0.f, 0.f, 0.f);
    int d = ix - e0;
    if (d >= 0 && d < 4) ((float*)&o)[d] = val;
    *(float4*)(out + (size_t)f * 4) = o;

    size_t base = (size_t)2 * N * E_DIM;
    if (f < 2 * N) {
        int n2 = f >> 1;
        int k2 = f & 1;
        int ix2 = k2 ? idx1[n2] : idx0[n2];
        int rr2 = k2 ? r1[n2]   : r0[n2];
        float p = probs[f];
        out[base + f]         = (rr2 < cap) ? p : 0.0f;   // router_probs_masked
        out[base + 2 * N + f] = (float)ix2;               // top_k_indices
        out[base + 4 * N + f] = (float)rr2;               // final_rank
    }
    if (f == 0) out[base + 6 * N] = (float)cap;           // exp_capacity
}

extern "C" void kernel_launch(void* const* d_in, const int* in_sizes, int n_in,
                              void* d_out, int out_size, void* d_ws, size_t ws_size,
                              hipStream_t stream)
{
    const float* x  = (const float*)d_in[0];
    const float* wg = (const float*)d_in[1];
    const int N = in_sizes[0] / C_DIM;   // 16384 tokens

    // workspace layout (24*N bytes = 384 KB)
    char* ws = (char*)d_ws;
    int*   idx0  = (int*)ws;
    int*   idx1  = idx0 + N;
    float* probs = (float*)(idx1 + N);
    int*   r0    = (int*)(probs + 2 * N);
    int*   r1    = r0 + N;

    float* out = (float*)d_out;

    int cap = (int)((long long)2 * 2 * N / E_DIM);   // TOP_K * EVAL_CAPACITY * N / E
    if (cap < 4) cap = 4;

    k_router<<<N / TB, 256, 0, stream>>>(x, wg, idx0, idx1, probs, N);
    k_scan<<<2 * E_DIM, 64, 0, stream>>>(idx0, idx1, r0, r1, N);
    k_mask_tail<<<(N * 32) / 256, 256, 0, stream>>>(idx0, idx1, r0, r1, probs, out, N, cap);
}

// Round 4
// 359.109 us; speedup vs baseline: 1.0820x; 1.0820x over previous
//
#include <hip/hip_runtime.h>
#include <hip/hip_bf16.h>
#include <math.h>

#define C_DIM 2048
#define E_DIM 64
#define TB    32        // tokens per block (k_router)
#define KC    256       // k per LDS tile
#define LSTR  68        // logits row stride in floats (pad for alignment+banks)

typedef __attribute__((ext_vector_type(8))) short bf16x8;
typedef __attribute__((ext_vector_type(4))) float f32x4;

union cvt8 { bf16x8 v; __hip_bfloat162 h[4]; };

__device__ __forceinline__ bf16x8 pack8(float4 a, float4 b) {
    cvt8 u;
    u.h[0] = __float22bfloat162_rn(make_float2(a.x, a.y));
    u.h[1] = __float22bfloat162_rn(make_float2(a.z, a.w));
    u.h[2] = __float22bfloat162_rn(make_float2(b.x, b.y));
    u.h[3] = __float22bfloat162_rn(make_float2(b.z, b.w));
    return u.v;
}

__device__ __forceinline__ float dot16(float4 x0, float4 x1, float4 x2, float4 x3,
                                       float4 w0, float4 w1, float4 w2, float4 w3)
{
    float f;
    f = x0.x * w0.x;
    f = fmaf(x0.y, w0.y, f); f = fmaf(x0.z, w0.z, f); f = fmaf(x0.w, w0.w, f);
    f = fmaf(x1.x, w1.x, f); f = fmaf(x1.y, w1.y, f); f = fmaf(x1.z, w1.z, f);
    f = fmaf(x1.w, w1.w, f);
    f = fmaf(x2.x, w2.x, f); f = fmaf(x2.y, w2.y, f); f = fmaf(x2.z, w2.z, f);
    f = fmaf(x2.w, w2.w, f);
    f = fmaf(x3.x, w3.x, f); f = fmaf(x3.y, w3.y, f); f = fmaf(x3.z, w3.z, f);
    f = fmaf(x3.w, w3.w, f);
    return f;
}

// ---------------- K1: bf16-MFMA noisy logits -> top-4 candidates -> exact
// fp64 refine -> top-2 + softmax. Register-double-buffered staging. ----------
__launch_bounds__(256)
__global__ void k_router(const float* __restrict__ x, const float* __restrict__ w,
                         int* __restrict__ idx0, int* __restrict__ idx1,
                         float* __restrict__ probs, int N)
{
    __shared__ __align__(16) char smem[49152];
    short* xs = (short*)smem;                   // [TB][KC] bf16, swizzled granules
    short* ws = (short*)(smem + TB * KC * 2);   // [E_DIM][KC]

    const int tid  = threadIdx.x;
    const int lane = tid & 63;
    const int wid  = tid >> 6;
    const int quad = lane >> 4;
    const int l15  = lane & 15;
    const int t0   = blockIdx.x * TB;
    const int tq   = (wid & 1) * 16;     // wave's token base (m-tile)
    const int e0   = (wid >> 1) * 32;    // wave's expert base (two n-tiles)

    f32x4 acc0 = {0.f, 0.f, 0.f, 0.f};
    f32x4 acc1 = {0.f, 0.f, 0.f, 0.f};

    float4 xr[4][2], wr[8][2];   // staged registers (double-buffer vs LDS)

    auto issue = [&](int kb) {
#pragma unroll
        for (int i = 0; i < 4; ++i) {
            int id = tid + 256 * i;
            int r = id >> 5, g = id & 31;
            const float* s = x + (size_t)(t0 + r) * C_DIM + kb + g * 8;
            xr[i][0] = *(const float4*)s;
            xr[i][1] = *(const float4*)(s + 4);
        }
#pragma unroll
        for (int i = 0; i < 8; ++i) {
            int id = tid + 256 * i;
            int r = id >> 5, g = id & 31;
            const float* s = w + (size_t)r * C_DIM + kb + g * 8;
            wr[i][0] = *(const float4*)s;
            wr[i][1] = *(const float4*)(s + 4);
        }
    };
    auto commit = [&]() {
#pragma unroll
        for (int i = 0; i < 4; ++i) {
            int id = tid + 256 * i;
            int r = id >> 5, g = id & 31;
            *(bf16x8*)&xs[r * KC + ((g ^ (r & 7)) * 8)] = pack8(xr[i][0], xr[i][1]);
        }
#pragma unroll
        for (int i = 0; i < 8; ++i) {
            int id = tid + 256 * i;
            int r = id >> 5, g = id & 31;
            *(bf16x8*)&ws[r * KC + ((g ^ (r & 7)) * 8)] = pack8(wr[i][0], wr[i][1]);
        }
    };

    issue(0);
    for (int t = 0; t < C_DIM / KC; ++t) {
        commit();                 // waits on loads issued one tile ago
        __syncthreads();          // tile t visible to all
        if (t < C_DIM / KC - 1) issue((t + 1) * KC);   // overlap with MFMA below

        const int ar  = tq + l15;
        const int br0 = e0 + l15;
        const int br1 = e0 + 16 + l15;
#pragma unroll
        for (int s = 0; s < KC / 32; ++s) {
            int g = s * 4 + quad;
            bf16x8 af  = *(const bf16x8*)&xs[ar  * KC + ((g ^ (ar  & 7)) * 8)];
            bf16x8 bf0 = *(const bf16x8*)&ws[br0 * KC + ((g ^ (br0 & 7)) * 8)];
            bf16x8 bf1 = *(const bf16x8*)&ws[br1 * KC + ((g ^ (br1 & 7)) * 8)];
            acc0 = __builtin_amdgcn_mfma_f32_16x16x32_bf16(af, bf0, acc0, 0, 0, 0);
            acc1 = __builtin_amdgcn_mfma_f32_16x16x32_bf16(af, bf1, acc1, 0, 0, 0);
        }
        __syncthreads();          // all waves done reading tile t
    }

    // ---- noisy logits -> LDS ----
    float*  L    = (float*)smem;                             // [TB][LSTR]
    int*    cand = (int*)(smem + TB * LSTR * 4);             // [TB][4]
    double* dsum = (double*)(smem + TB * LSTR * 4 + TB * 16); // [TB*4][2]

#pragma unroll
    for (int reg = 0; reg < 4; ++reg) {
        int t = tq + quad * 4 + reg;     // C/D: row = quad*4+reg, col = lane&15
        L[t * LSTR + e0 + l15]      = acc0[reg];
        L[t * LSTR + e0 + 16 + l15] = acc1[reg];
    }
    __syncthreads();

    // ---- top-4 per token: one thread scans its token's 64 logits ----
    if (tid < TB) {
        const float* row = &L[tid * LSTR];
        float v0 = -3e38f, v1 = -3e38f, v2 = -3e38f, v3 = -3e38f;
        int   b0 = 64, b1 = 64, b2 = 64, b3 = 64;
#pragma unroll
        for (int e = 0; e < E_DIM; e += 4) {
            float4 q = *(const float4*)(row + e);
#pragma unroll
            for (int m = 0; m < 4; ++m) {
                float vv = ((float*)&q)[m];
                int   ee = e + m;
                if (vv > v3 || (vv == v3 && ee < b3)) {
                    if (vv > v0 || (vv == v0 && ee < b0)) {
                        v3 = v2; b3 = b2; v2 = v1; b2 = b1; v1 = v0; b1 = b0;
                        v0 = vv; b0 = ee;
                    } else if (vv > v1 || (vv == v1 && ee < b1)) {
                        v3 = v2; b3 = b2; v2 = v1; b2 = b1; v1 = vv; b1 = ee;
                    } else if (vv > v2 || (vv == v2 && ee < b2)) {
                        v3 = v2; b3 = b2; v2 = vv; b2 = ee;
                    } else { v3 = vv; b3 = ee; }
                }
            }
        }
        cand[tid * 4]     = b0;
        cand[tid * 4 + 1] = b1;
        cand[tid * 4 + 2] = b2;
        cand[tid * 4 + 3] = b3;
    }
    __syncthreads();

    // ---- exact refine: batched loads, 2 independent fp64 partials ----
    {
        int p = tid >> 1;        // (token, cand) pair 0..127
        int h = tid & 1;         // k-half
        int t = p >> 2;
        int c = cand[t * 4 + (p & 3)];
        const float* xp = x + (size_t)(t0 + t) * C_DIM + h * (C_DIM / 2);
        const float* wp = w + (size_t)c * C_DIM + h * (C_DIM / 2);
        double d0 = 0.0, d1 = 0.0;
#pragma unroll 4
        for (int k = 0; k < C_DIM / 2; k += 32) {
            float4 xa[8], wa[8];
#pragma unroll
            for (int m = 0; m < 8; ++m) xa[m] = *(const float4*)(xp + k + 4 * m);
#pragma unroll
            for (int m = 0; m < 8; ++m) wa[m] = *(const float4*)(wp + k + 4 * m);
            d0 += (double)dot16(xa[0], xa[1], xa[2], xa[3], wa[0], wa[1], wa[2], wa[3]);
            d1 += (double)dot16(xa[4], xa[5], xa[6], xa[7], wa[4], wa[5], wa[6], wa[7]);
        }
        dsum[p * 2 + h] = d0 + d1;
    }
    __syncthreads();

    // ---- exact top-2 among candidates (ties: lower expert index) ----
    if (tid < TB) {
        int t = tid;
        double v[4]; int e[4];
#pragma unroll
        for (int c = 0; c < 4; ++c) {
            v[c] = dsum[(t * 4 + c) * 2] + dsum[(t * 4 + c) * 2 + 1];
            e[c] = cand[t * 4 + c];
        }
        int b0 = 0;
#pragma unroll
        for (int c = 1; c < 4; ++c)
            if (v[c] > v[b0] || (v[c] == v[b0] && e[c] < e[b0])) b0 = c;
        int b1 = (b0 == 0) ? 1 : 0;
#pragma unroll
        for (int c = 0; c < 4; ++c) {
            if (c == b0 || c == b1) continue;
            if (v[c] > v[b1] || (v[c] == v[b1] && e[c] < e[b1])) b1 = c;
        }
        int n = t0 + t;
        float p0 = 1.0f / (1.0f + expf((float)(v[b1] - v[b0])));
        idx0[n] = e[b0];
        idx1[n] = e[b1];
        probs[2 * n]     = p0;
        probs[2 * n + 1] = 1.0f - p0;
    }
}

// ---------------- K2: rank scan, 128 blocks x 4 waves, one load round ------
__launch_bounds__(256)
__global__ void k_scan(const int* __restrict__ idx0, const int* __restrict__ idx1,
                       int* __restrict__ r0, int* __restrict__ r1, int N)
{
    const int e    = blockIdx.x >> 1;
    const int pass = blockIdx.x & 1;
    const int tid  = threadIdx.x;
    const int lane = tid & 63;
    const int wid  = tid >> 6;
    __shared__ int cnt[4], cnt0[4];

    const int* idx = pass ? idx1 : idx0;
    int*       r   = pass ? r1   : r0;
    const int  seg = wid * (N / 4);          // 4096 tokens per wave
    const unsigned long long lt = (1ull << lane) - 1ull;

    // cache this wave's quarter in registers (single latency round)
    int v[64];
#pragma unroll
    for (int j = 0; j < 64; ++j) v[j] = idx[seg + j * 64 + lane];

    int my = 0;
#pragma unroll
    for (int j = 0; j < 64; ++j) my += __popcll(__ballot(v[j] == e));

    int my0 = 0;
    if (pass) {
        const int* q = idx0 + seg;
#pragma unroll
        for (int j = 0; j < 64; j += 16) {
            int u[16];
#pragma unroll
            for (int m = 0; m < 16; ++m) u[m] = q[(j + m) * 64 + lane];
#pragma unroll
            for (int m = 0; m < 16; ++m) my0 += __popcll(__ballot(u[m] == e));
        }
    }
    if (lane == 0) { cnt[wid] = my; cnt0[wid] = my0; }
    __syncthreads();

    int running = pass ? (cnt0[0] + cnt0[1] + cnt0[2] + cnt0[3]) : 0;
#pragma unroll
    for (int w2 = 0; w2 < 4; ++w2) if (w2 < wid) running += cnt[w2];

#pragma unroll
    for (int j = 0; j < 64; ++j) {
        bool p = (v[j] == e);
        unsigned long long b = __ballot(p);
        if (p) r[seg + j * 64 + lane] = running + __popcll(b & lt);
        running += __popcll(b);
    }
}

// ---------------- K3: one-hot capacity mask + tail outputs (fused) ----------
__launch_bounds__(256)
__global__ void k_mask_tail(const int* __restrict__ idx0, const int* __restrict__ idx1,
                            const int* __restrict__ r0, const int* __restrict__ r1,
                            const float* __restrict__ probs,
                            float* __restrict__ out, int N, int cap)
{
    int f = blockIdx.x * 256 + threadIdx.x;   // float4 index, total N*32
    int n   = f >> 5;
    int rem = (f & 31) * 4;       // 0..124 within the token's 128 floats
    int k   = rem >> 6;           // 0 or 1
    int e0  = rem & 63;
    int ix = k ? idx1[n] : idx0[n];
    int rr = k ? r1[n]   : r0[n];
    float val = (rr < cap) ? 1.0f : 0.0f;
    float4 o = make_float4(0.f, 0.f, 0.f, 0.f);
    int d = ix - e0;
    if (d >= 0 && d < 4) ((float*)&o)[d] = val;
    *(float4*)(out + (size_t)f * 4) = o;

    size_t base = (size_t)2 * N * E_DIM;
    if (f < 2 * N) {
        int n2 = f >> 1;
        int k2 = f & 1;
        int ix2 = k2 ? idx1[n2] : idx0[n2];
        int rr2 = k2 ? r1[n2]   : r0[n2];
        float p = probs[f];
        out[base + f]         = (rr2 < cap) ? p : 0.0f;   // router_probs_masked
        out[base + 2 * N + f] = (float)ix2;               // top_k_indices
        out[base + 4 * N + f] = (float)rr2;               // final_rank
    }
    if (f == 0) out[base + 6 * N] = (float)cap;           // exp_capacity
}

extern "C" void kernel_launch(void* const* d_in, const int* in_sizes, int n_in,
                              void* d_out, int out_size, void* d_ws, size_t ws_size,
                              hipStream_t stream)
{
    const float* x  = (const float*)d_in[0];
    const float* wg = (const float*)d_in[1];
    const int N = in_sizes[0] / C_DIM;   // 16384 tokens

    // workspace layout (24*N bytes = 384 KB)
    char* ws = (char*)d_ws;
    int*   idx0  = (int*)ws;
    int*   idx1  = idx0 + N;
    float* probs = (float*)(idx1 + N);
    int*   r0    = (int*)(probs + 2 * N);
    int*   r1    = r0 + N;

    float* out = (float*)d_out;

    int cap = (int)((long long)2 * 2 * N / E_DIM);   // TOP_K * EVAL_CAPACITY * N / E
    if (cap < 4) cap = 4;

    k_router<<<N / TB, 256, 0, stream>>>(x, wg, idx0, idx1, probs, N);
    k_scan<<<2 * E_DIM, 256, 0, stream>>>(idx0, idx1, r0, r1, N);
    k_mask_tail<<<(N * 32) / 256, 256, 0, stream>>>(idx0, idx1, r0, r1, probs, out, N, cap);
}